// Round 6
// baseline (101.883 us; speedup 1.0000x reference)
//
#include <hip/hip_runtime.h>
#include <hip/hip_bf16.h>

#define N 8192
#define D 128
#define T64 64
#define NT64 (N / T64)                 // 128 tile-rows of 64
// NPAIR = 128*129/2 = 8256 = 2112*3 + 960*2 over 3072 waves

typedef __attribute__((ext_vector_type(4))) int   intx4;
typedef unsigned long long u64;

static __device__ inline float softplus_of(const float* __restrict__ phi) {
    float p = phi[0];
    return (p > 20.f) ? p : log1pf(__expf(p));
}

// k1: FUSED prep — out = x + var*noise; q8[r,k] = int8(rint(16*x[r,k]));
// sqv[r] = sum_k q^2 (exact int); rowsum zero-init.
// One thread per 8 elements: N*16/256 = 512 blocks.
__global__ __launch_bounds__(256) void k1_prep(
        const float* __restrict__ x, const float* __restrict__ phi,
        const float* __restrict__ noise, float* __restrict__ out,
        signed char* __restrict__ q8, int* __restrict__ sqv,
        float* __restrict__ rowsum) {
    int gid = blockIdx.x * 256 + threadIdx.x;
    int row = gid >> 4;
    int gc  = gid & 15;
    float var = softplus_of(phi);

    const float* xs = x     + (size_t)row * D + gc * 8;
    const float* ns = noise + (size_t)row * D + gc * 8;
    float4 u  = *(const float4*)xs, v  = *(const float4*)(xs + 4);
    float4 nu = *(const float4*)ns, nv = *(const float4*)(ns + 4);

    float4 o0, o1;
    o0.x = u.x + var * nu.x; o0.y = u.y + var * nu.y;
    o0.z = u.z + var * nu.z; o0.w = u.w + var * nu.w;
    o1.x = v.x + var * nv.x; o1.y = v.y + var * nv.y;
    o1.z = v.z + var * nv.z; o1.w = v.w + var * nv.w;
    float* od = out + (size_t)row * D + gc * 8;
    *(float4*)od = o0; *(float4*)(od + 4) = o1;

    float f[8] = {u.x, u.y, u.z, u.w, v.x, v.y, v.z, v.w};
    u64 pack = 0;
    int s = 0;
    #pragma unroll
    for (int k = 0; k < 8; k++) {
        float c = fminf(fmaxf(f[k] * 16.f, -127.f), 127.f);
        int q = (int)rintf(c);
        s += q * q;
        pack |= ((u64)(q & 255)) << (8 * k);
    }
    *(u64*)&q8[(size_t)row * D + gc * 8] = pack;

    #pragma unroll
    for (int m = 1; m < 16; m <<= 1) s += __shfl_xor(s, m, 64);
    if (gc == 0) { sqv[row] = s; rowsum[row] = 0.f; }
}

// k2: barrier-free symmetric Gram on int8. 3072 independent waves (768
// blocks, 3/CU, 3 waves/SIMD); wave w owns 3 (2 for w>=2112) consecutive
// upper-tri 64x64 tile-pairs. A/B fragments in registers (16B loads, one
// cache line per row); next pair's B prefetched per-nt during compute.
// d2s = sq_i + sq_j - 2*dot is EXACT int (diag exactly 0, no clamp).
// Row sums of ti in registers (flushed on ti change); column sums -> rows
// of tj via symmetry, flushed per pair. No LDS, no barriers.
__global__ __launch_bounds__(256, 3) void k2_gram(
        const signed char* __restrict__ q8, const float* __restrict__ phi,
        const int* __restrict__ sqv, float* __restrict__ rowsum) {
    const int w    = blockIdx.x * 4 + (threadIdx.x >> 6);
    const int lane = threadIdx.x & 63;
    const int lrow = lane & 15;
    const int quad = lane >> 4;

    const int cnt = (w < 2112) ? 3 : 2;
    int start     = (w < 2112) ? 3 * w : 2 * w + 2112;
    int ti = 0, rem = start, len = NT64;
    while (rem >= len) { rem -= len; ++ti; --len; }
    int tj = ti + rem;

    float var = softplus_of(phi);
    // exp(-0.5*d2/var), d2 = d2s/256 (scale 16^2), ln->log2 folded:
    const float c2 = ((-0.5f / var) * 1.4426950408889634f) * (1.f / 256.f);

    intx4 af[4][2], bf[4][2];
    int   sqi[4][4];
    float rowAcc[4][4];
    int   sje[4], sjeN[4];
    int curTi = -1;

    // prologue: B fragments + sje for the first pair
    #pragma unroll
    for (int nt = 0; nt < 4; nt++) {
        const signed char* br = q8 + (size_t)(tj * T64 + nt * 16 + lrow) * D + quad * 16;
        bf[nt][0] = *(const intx4*)br;
        bf[nt][1] = *(const intx4*)(br + 64);
        sje[nt] = sqv[tj * T64 + nt * 16 + lrow];
    }

    for (int r = 0; r < cnt; ++r) {
        const int iB = ti * T64, jB = tj * T64;

        if (ti != curTi) {
            if (curTi >= 0) {  // flush previous ti's row sums
                const int pB = curTi * T64;
                #pragma unroll
                for (int mt = 0; mt < 4; mt++)
                    #pragma unroll
                    for (int reg = 0; reg < 4; reg++) {
                        float vv = rowAcc[mt][reg];
                        #pragma unroll
                        for (int m = 1; m < 16; m <<= 1) vv += __shfl_xor(vv, m, 64);
                        if (lrow == 0)
                            atomicAdd(&rowsum[pB + mt * 16 + quad * 4 + reg], vv);
                    }
            }
            #pragma unroll
            for (int mt = 0; mt < 4; mt++) {
                const signed char* ar =
                    q8 + (size_t)(iB + mt * 16 + lrow) * D + quad * 16;
                af[mt][0] = *(const intx4*)ar;
                af[mt][1] = *(const intx4*)(ar + 64);
            }
            #pragma unroll
            for (int mt = 0; mt < 4; mt++)
                #pragma unroll
                for (int reg = 0; reg < 4; reg++) {
                    sqi[mt][reg] = sqv[iB + mt * 16 + quad * 4 + reg];
                    rowAcc[mt][reg] = 0.f;
                }
            curTi = ti;
        }

        int nti = ti, ntj = tj + 1;
        if (ntj == NT64) { ++nti; ntj = nti; }
        const bool more = (r + 1 < cnt);

        float colAcc[4] = {0.f, 0.f, 0.f, 0.f};
        #pragma unroll
        for (int nt = 0; nt < 4; nt++) {
            intx4 acc[4] = {};
            #pragma unroll
            for (int kk = 0; kk < 2; kk++)
                #pragma unroll
                for (int mt = 0; mt < 4; mt++)
                    acc[mt] = __builtin_amdgcn_mfma_i32_16x16x64_i8(
                        af[mt][kk], bf[nt][kk], acc[mt], 0, 0, 0);

            // bf[nt] fully consumed -> prefetch next pair's bf[nt] now; it
            // lands during the remaining ~3/4 of this pair's work.
            if (more) {
                const signed char* br =
                    q8 + (size_t)(ntj * T64 + nt * 16 + lrow) * D + quad * 16;
                bf[nt][0] = *(const intx4*)br;
                bf[nt][1] = *(const intx4*)(br + 64);
                if (nt == 3) {
                    #pragma unroll
                    for (int n2 = 0; n2 < 4; n2++)
                        sjeN[n2] = sqv[ntj * T64 + n2 * 16 + lrow];
                }
            }

            // epilogue: p = exp2(d2s * c2); d2s exact int >= 0.
            // C/D layout: col = lane&15, row = quad*4 + reg  [learn_hip m89]
            int sj = sje[nt];
            #pragma unroll
            for (int mt = 0; mt < 4; mt++)
                #pragma unroll
                for (int reg = 0; reg < 4; reg++) {
                    int d2s = sqi[mt][reg] + sj - 2 * acc[mt][reg];
                    float p = __builtin_amdgcn_exp2f((float)d2s * c2);
                    rowAcc[mt][reg] += p;
                    colAcc[nt]      += p;
                }
        }

        if (ti != tj) {  // strictly-upper: column sums -> rows of tj
            #pragma unroll
            for (int nt = 0; nt < 4; nt++) {
                float vv = colAcc[nt];
                vv += __shfl_xor(vv, 16, 64);
                vv += __shfl_xor(vv, 32, 64);
                if (quad == 0)
                    atomicAdd(&rowsum[jB + nt * 16 + lrow], vv);
            }
        }

        if (more) {
            #pragma unroll
            for (int nt = 0; nt < 4; nt++) sje[nt] = sjeN[nt];
        }
        ti = nti; tj = ntj;
    }

    // final row flush
    {
        const int pB = curTi * T64;
        #pragma unroll
        for (int mt = 0; mt < 4; mt++)
            #pragma unroll
            for (int reg = 0; reg < 4; reg++) {
                float vv = rowAcc[mt][reg];
                #pragma unroll
                for (int m = 1; m < 16; m <<= 1) vv += __shfl_xor(vv, m, 64);
                if (lrow == 0)
                    atomicAdd(&rowsum[pB + mt * 16 + quad * 4 + reg], vv);
            }
    }
}

// k3: IXT = (ln N - mean_i ln rowsum[i]) / ln 2
__global__ __launch_bounds__(1024) void k3_final(
        const float* __restrict__ rowsum, float* __restrict__ out_ixt) {
    __shared__ float red[16];
    int t = threadIdx.x;
    float local = 0.f;
    for (int i = t; i < N; i += 1024) local += logf(rowsum[i]);
    #pragma unroll
    for (int m = 1; m < 64; m <<= 1) local += __shfl_xor(local, m, 64);
    if ((t & 63) == 0) red[t >> 6] = local;
    __syncthreads();
    if (t < 16) {
        float v = red[t];
        #pragma unroll
        for (int m = 1; m < 16; m <<= 1) v += __shfl_xor(v, m, 64);
        if (t == 0) {
            float kde = v / (float)N;
            out_ixt[0] = (logf((float)N) - kde) * 1.4426950408889634f;
        }
    }
}

extern "C" void kernel_launch(void* const* d_in, const int* in_sizes, int n_in,
                              void* d_out, int out_size, void* d_ws, size_t ws_size,
                              hipStream_t stream) {
    const float* x     = (const float*)d_in[0];
    const float* phi   = (const float*)d_in[1];
    const float* noise = (const float*)d_in[2];
    float* out = (float*)d_out;

    // d_ws layout (~1.1 MB of the ~268 MB workspace):
    float* rowsum = (float*)d_ws;                      // N floats
    int*   sqv    = (int*)(rowsum + N);                // N ints
    signed char* q8 = (signed char*)(sqv + N);         // N*D int8 = 1 MB

    k1_prep<<<(N * 16) / 256, 256, 0, stream>>>(x, phi, noise, out, q8, sqv, rowsum);
    k2_gram<<<768, 256, 0, stream>>>(q8, phi, sqv, rowsum);
    k3_final<<<1, 1024, 0, stream>>>(rowsum, out + (size_t)N * D);
}

// Round 7
// 92.251 us; speedup vs baseline: 1.1044x; 1.1044x over previous
//
#include <hip/hip_runtime.h>
#include <hip/hip_bf16.h>

#define N 8192
#define D 128
#define T64 64
#define NT64 (N / T64)   // 128 tile-rows; NPAIR = 128*129/2 = 8256 = 2112*3 + 960*2

typedef __attribute__((ext_vector_type(4))) int intx4;
typedef unsigned long long u64;

static __device__ inline float softplus_of(const float* __restrict__ phi) {
    float p = phi[0];
    return (p > 20.f) ? p : log1pf(__expf(p));
}

// k1: FUSED prep — out = x + var*noise; q8[r,k] = int8(rint(16*x[r,k]));
// sqv[r] = sum_k q^2 (exact int); rowsum zero-init.
__global__ __launch_bounds__(256) void k1_prep(
        const float* __restrict__ x, const float* __restrict__ phi,
        const float* __restrict__ noise, float* __restrict__ out,
        signed char* __restrict__ q8, int* __restrict__ sqv,
        float* __restrict__ rowsum) {
    int gid = blockIdx.x * 256 + threadIdx.x;
    int row = gid >> 4;
    int gc  = gid & 15;
    float var = softplus_of(phi);

    const float* xs = x     + (size_t)row * D + gc * 8;
    const float* ns = noise + (size_t)row * D + gc * 8;
    float4 u  = *(const float4*)xs, v  = *(const float4*)(xs + 4);
    float4 nu = *(const float4*)ns, nv = *(const float4*)(ns + 4);

    float4 o0, o1;
    o0.x = u.x + var * nu.x; o0.y = u.y + var * nu.y;
    o0.z = u.z + var * nu.z; o0.w = u.w + var * nu.w;
    o1.x = v.x + var * nv.x; o1.y = v.y + var * nv.y;
    o1.z = v.z + var * nv.z; o1.w = v.w + var * nv.w;
    float* od = out + (size_t)row * D + gc * 8;
    *(float4*)od = o0; *(float4*)(od + 4) = o1;

    float f[8] = {u.x, u.y, u.z, u.w, v.x, v.y, v.z, v.w};
    u64 pack = 0;
    int s = 0;
    #pragma unroll
    for (int k = 0; k < 8; k++) {
        float c = fminf(fmaxf(f[k] * 16.f, -127.f), 127.f);
        int q = (int)rintf(c);
        s += q * q;
        pack |= ((u64)(q & 255)) << (8 * k);
    }
    *(u64*)&q8[(size_t)row * D + gc * 8] = pack;

    #pragma unroll
    for (int m = 1; m < 16; m <<= 1) s += __shfl_xor(s, m, 64);
    if (gc == 0) { sqv[row] = s; rowsum[row] = 0.f; }
}

// k2: screened symmetric int8 Gram. Per 64x64 tile-pair: 32 MFMA, then a
// 4-VALU/element integer screen (d2s = sqi+sj-2dot, EXACT distance^2 of the
// quantized vectors, scale 256). Pairs with min d2s >= Ts are certified to
// contribute < 2^-30 each to any rowsum and are dropped; flagged nt-columns
// (the 128 diagonal tiles + any genuinely close pair) take the exact exp2
// slow path with atomics. Barrier-free, no LDS; 768 blocks (3/CU).
__global__ __launch_bounds__(256, 3) void k2_gram(
        const signed char* __restrict__ q8, const float* __restrict__ phi,
        const int* __restrict__ sqv, float* __restrict__ rowsum) {
    const int w    = blockIdx.x * 4 + (threadIdx.x >> 6);
    const int lane = threadIdx.x & 63;
    const int lrow = lane & 15;
    const int quad = lane >> 4;

    const int cnt = (w < 2112) ? 3 : 2;
    int start     = (w < 2112) ? 3 * w : 2 * w + 2112;
    int ti = 0, rem = start, len = NT64;
    while (rem >= len) { rem -= len; ++ti; --len; }
    int tj = ti + rem;

    float var = softplus_of(phi);
    // p = exp(-0.5*(d2s/256)/var) = exp2(d2s * c2)
    const float c2 = ((-0.5f / var) * 1.4426950408889634f) * (1.f / 256.f);
    // prune iff contribution <= 2^-30  <=>  d2s >= 30/(-c2)
    const int Ts = (int)ceilf(30.f / (-c2));

    intx4 af[4][2], bf[4][2];
    int   sqi[4][4];
    int curTi = -1;

    // prologue: B fragments for the first pair (one 64B line per row per load)
    #pragma unroll
    for (int nt = 0; nt < 4; nt++) {
        const signed char* br = q8 + (size_t)(tj * T64 + nt * 16 + lrow) * D + quad * 16;
        bf[nt][0] = *(const intx4*)br;
        bf[nt][1] = *(const intx4*)(br + 64);
    }

    for (int r = 0; r < cnt; ++r) {
        const int iB = ti * T64, jB = tj * T64;

        int sje[4];
        #pragma unroll
        for (int nt = 0; nt < 4; nt++)
            sje[nt] = sqv[jB + nt * 16 + lrow];

        if (ti != curTi) {
            #pragma unroll
            for (int mt = 0; mt < 4; mt++) {
                const signed char* ar =
                    q8 + (size_t)(iB + mt * 16 + lrow) * D + quad * 16;
                af[mt][0] = *(const intx4*)ar;
                af[mt][1] = *(const intx4*)(ar + 64);
            }
            #pragma unroll
            for (int mt = 0; mt < 4; mt++)
                #pragma unroll
                for (int reg = 0; reg < 4; reg++)
                    sqi[mt][reg] = sqv[iB + mt * 16 + quad * 4 + reg];
            curTi = ti;
        }

        int nti = ti, ntj = tj + 1;
        if (ntj == NT64) { ++nti; ntj = nti; }
        const bool more = (r + 1 < cnt);

        #pragma unroll
        for (int nt = 0; nt < 4; nt++) {
            intx4 acc[4] = {};
            #pragma unroll
            for (int kk = 0; kk < 2; kk++)
                #pragma unroll
                for (int mt = 0; mt < 4; mt++)
                    acc[mt] = __builtin_amdgcn_mfma_i32_16x16x64_i8(
                        af[mt][kk], bf[nt][kk], acc[mt], 0, 0, 0);

            // bf[nt] consumed -> prefetch next pair's bf[nt] (lands during
            // the remaining ~3/4 of this pair's work; no barrier ever drains)
            if (more) {
                const signed char* br =
                    q8 + (size_t)(ntj * T64 + nt * 16 + lrow) * D + quad * 16;
                bf[nt][0] = *(const intx4*)br;
                bf[nt][1] = *(const intx4*)(br + 64);
            }

            // ---- integer screen: min d2s over this nt-column ----
            // C/D layout: col = lane&15, row = quad*4 + reg  [learn_hip m89]
            const int sj = sje[nt];
            int mn = 0x7fffffff;
            #pragma unroll
            for (int mt = 0; mt < 4; mt++)
                #pragma unroll
                for (int reg = 0; reg < 4; reg++) {
                    int d2s = sqi[mt][reg] + sj - (acc[mt][reg] << 1);
                    mn = min(mn, d2s);
                }

            if (__any(mn < Ts)) {
                // exact slow path (diagonal tiles + genuinely close pairs)
                float colv = 0.f;
                #pragma unroll
                for (int mt = 0; mt < 4; mt++)
                    #pragma unroll
                    for (int reg = 0; reg < 4; reg++) {
                        int d2s = sqi[mt][reg] + sj - (acc[mt][reg] << 1);
                        float p = __builtin_amdgcn_exp2f((float)d2s * c2);
                        colv += p;
                        float rv = p;
                        rv += __shfl_xor(rv, 1, 64);
                        rv += __shfl_xor(rv, 2, 64);
                        rv += __shfl_xor(rv, 4, 64);
                        rv += __shfl_xor(rv, 8, 64);
                        if (lrow == 0)
                            atomicAdd(&rowsum[iB + mt * 16 + quad * 4 + reg], rv);
                    }
                if (ti != tj) {  // symmetric column contribution
                    colv += __shfl_xor(colv, 16, 64);
                    colv += __shfl_xor(colv, 32, 64);
                    if (quad == 0)
                        atomicAdd(&rowsum[jB + nt * 16 + lrow], colv);
                }
            }
        }

        ti = nti; tj = ntj;
    }
}

// k3: IXT = (ln N - mean_i ln rowsum[i]) / ln 2
__global__ __launch_bounds__(1024) void k3_final(
        const float* __restrict__ rowsum, float* __restrict__ out_ixt) {
    __shared__ float red[16];
    int t = threadIdx.x;
    float local = 0.f;
    for (int i = t; i < N; i += 1024) local += logf(rowsum[i]);
    #pragma unroll
    for (int m = 1; m < 64; m <<= 1) local += __shfl_xor(local, m, 64);
    if ((t & 63) == 0) red[t >> 6] = local;
    __syncthreads();
    if (t < 16) {
        float v = red[t];
        #pragma unroll
        for (int m = 1; m < 16; m <<= 1) v += __shfl_xor(v, m, 64);
        if (t == 0) {
            float kde = v / (float)N;
            out_ixt[0] = (logf((float)N) - kde) * 1.4426950408889634f;
        }
    }
}

extern "C" void kernel_launch(void* const* d_in, const int* in_sizes, int n_in,
                              void* d_out, int out_size, void* d_ws, size_t ws_size,
                              hipStream_t stream) {
    const float* x     = (const float*)d_in[0];
    const float* phi   = (const float*)d_in[1];
    const float* noise = (const float*)d_in[2];
    float* out = (float*)d_out;

    float* rowsum = (float*)d_ws;                      // N floats
    int*   sqv    = (int*)(rowsum + N);                // N ints
    signed char* q8 = (signed char*)(sqv + N);         // N*D int8 = 1 MB

    k1_prep<<<(N * 16) / 256, 256, 0, stream>>>(x, phi, noise, out, q8, sqv, rowsum);
    k2_gram<<<768, 256, 0, stream>>>(q8, phi, sqv, rowsum);
    k3_final<<<1, 1024, 0, stream>>>(rowsum, out + (size_t)N * D);
}